// Round 2
// baseline (1112.103 us; speedup 1.0000x reference)
//
#include <hip/hip_runtime.h>
#include <cmath>

#define B_   16
#define C_   256
#define HW_  64
#define N_   4096          // 64*64
#define NH_  8
#define HD_  32
#define M_   (B_ * N_)     // 65536
#define QKVC (3 * C_)      // 768
#define EPS_ 1e-6f

// Workspace plan (202 MB total):
//   qkv_buf [M, 768] f32  — q|k|v per token; after k_attn_out the q-slot
//                           (cols 0..255) is REUSED as the attention output.
//   kv_buf  [128, 32, 32] — per-(b,h) k^T v
//   ksum_buf[128, 32]     — per-(b,h) sum_j k_j

// ---------------------------------------------------------------------------
// K1: qkv = xf @ qkv_w^T + qkv_b
// ---------------------------------------------------------------------------
__global__ __launch_bounds__(256) void k_qkv_gemm(
    const float* __restrict__ x, const float* __restrict__ w,
    const float* __restrict__ bias, float* __restrict__ qkv) {
  __shared__ float As[16][64];
  __shared__ float Bs[16][64];
  const int m0 = blockIdx.x * 64;
  const int b = m0 / N_;
  const int n0 = m0 % N_;
  const int col0 = blockIdx.y * 64;
  const int tid = threadIdx.x;
  const int ty = tid >> 4, tx = tid & 15;

  const int a_k = tid >> 4;         // 0..15
  const int a_n = (tid & 15) * 4;   // 0..60
  const int b_col = tid >> 2;       // 0..63
  const int b_k = (tid & 3) * 4;    // 0..12

  float acc[4][4] = {};

  for (int k0 = 0; k0 < C_; k0 += 16) {
    float4 av = *reinterpret_cast<const float4*>(
        &x[((size_t)b * C_ + (k0 + a_k)) * N_ + n0 + a_n]);
    *reinterpret_cast<float4*>(&As[a_k][a_n]) = av;
    float4 bv = *reinterpret_cast<const float4*>(
        &w[(size_t)(col0 + b_col) * C_ + k0 + b_k]);
    Bs[b_k + 0][b_col] = bv.x;
    Bs[b_k + 1][b_col] = bv.y;
    Bs[b_k + 2][b_col] = bv.z;
    Bs[b_k + 3][b_col] = bv.w;
    __syncthreads();
#pragma unroll
    for (int kk = 0; kk < 16; ++kk) {
      float4 a = *reinterpret_cast<const float4*>(&As[kk][ty * 4]);
      float4 bq = *reinterpret_cast<const float4*>(&Bs[kk][tx * 4]);
      float ar[4] = {a.x, a.y, a.z, a.w};
      float br[4] = {bq.x, bq.y, bq.z, bq.w};
#pragma unroll
      for (int i = 0; i < 4; ++i)
#pragma unroll
        for (int j = 0; j < 4; ++j) acc[i][j] += ar[i] * br[j];
    }
    __syncthreads();
  }

  const int colg = col0 + tx * 4;
  const float b0 = bias[colg + 0], b1 = bias[colg + 1];
  const float b2 = bias[colg + 2], b3 = bias[colg + 3];
#pragma unroll
  for (int i = 0; i < 4; ++i) {
    float4 o = make_float4(acc[i][0] + b0, acc[i][1] + b1, acc[i][2] + b2,
                           acc[i][3] + b3);
    *reinterpret_cast<float4*>(&qkv[(size_t)(m0 + ty * 4 + i) * QKVC + colg]) = o;
  }
}

// ---------------------------------------------------------------------------
// K2: focusing feature map, in-place on q,k halves of qkv.
// ---------------------------------------------------------------------------
__global__ __launch_bounds__(256) void k_focus(float* __restrict__ qkv,
                                               const float* __restrict__ scale) {
  const int t = blockIdx.x;       // token
  const int c = threadIdx.x;      // channel
  const size_t base = (size_t)t * QKVC;
  const float sc = log1pf(expf(scale[c]));  // softplus

  float q = qkv[base + c];
  float k = qkv[base + C_ + c];
  q = (q > 0.f ? q : 0.f) + EPS_;
  k = (k > 0.f ? k : 0.f) + EPS_;
  q /= sc;
  k /= sc;
  const float q3 = q * q * q;
  const float k3 = k * k * k;

  float v0 = q * q, v1 = q3 * q3, v2 = k * k, v3 = k3 * k3;
#pragma unroll
  for (int off = 32; off > 0; off >>= 1) {
    v0 += __shfl_down(v0, off);
    v1 += __shfl_down(v1, off);
    v2 += __shfl_down(v2, off);
    v3 += __shfl_down(v3, off);
  }
  __shared__ float red[4][4];
  const int wave = threadIdx.x >> 6;
  const int lane = threadIdx.x & 63;
  if (lane == 0) {
    red[wave][0] = v0;
    red[wave][1] = v1;
    red[wave][2] = v2;
    red[wave][3] = v3;
  }
  __syncthreads();
  const float sq2 = red[0][0] + red[1][0] + red[2][0] + red[3][0];
  const float sq6 = red[0][1] + red[1][1] + red[2][1] + red[3][1];
  const float sk2 = red[0][2] + red[1][2] + red[2][2] + red[3][2];
  const float sk6 = red[0][3] + red[1][3] + red[2][3] + red[3][3];

  qkv[base + c] = q3 * (sqrtf(sq2) / sqrtf(sq6));
  qkv[base + C_ + c] = k3 * (sqrtf(sk2) / sqrtf(sk6));
}

// ---------------------------------------------------------------------------
// K3: per (b,h): kv[c][d] = sum_j k[j][c]*v[j][d];  ksum[c] = sum_j k[j][c]
// ---------------------------------------------------------------------------
__global__ __launch_bounds__(256) void k_kv(const float* __restrict__ qkv,
                                            float* __restrict__ kvbuf,
                                            float* __restrict__ ksumbuf) {
  const int bh = blockIdx.x;
  const int b = bh >> 3, h = bh & 7;
  const int tid = threadIdx.x;
  __shared__ float ks[16][32];
  __shared__ float vs[16][32];
  const int c = tid >> 3;
  const int d0 = (tid & 7) * 4;
  float acc[4] = {0.f, 0.f, 0.f, 0.f};
  float ksum_acc = 0.f;

  for (int j0 = 0; j0 < N_; j0 += 16) {
    __syncthreads();
#pragma unroll
    for (int p = 0; p < 2; ++p) {
      const int f = tid + p * 256;
      const int jj = f >> 5, cc = f & 31;
      const size_t rb = ((size_t)(b * N_ + j0 + jj)) * QKVC + h * HD_;
      ks[jj][cc] = qkv[rb + C_ + cc];
      vs[jj][cc] = qkv[rb + 2 * C_ + cc];
    }
    __syncthreads();
#pragma unroll
    for (int jj = 0; jj < 16; ++jj) {
      const float kc = ks[jj][c];
#pragma unroll
      for (int p = 0; p < 4; ++p) acc[p] += kc * vs[jj][d0 + p];
    }
    if (tid < 32) {
#pragma unroll
      for (int jj = 0; jj < 16; ++jj) ksum_acc += ks[jj][tid];
    }
  }
#pragma unroll
  for (int p = 0; p < 4; ++p) kvbuf[bh * 1024 + c * 32 + d0 + p] = acc[p];
  if (tid < 32) ksumbuf[bh * 32 + tid] = ksum_acc;
}

// ---------------------------------------------------------------------------
// K4: out[i][d] = z_i * sum_c q[i][c]*kv[c][d], written IN-PLACE into the
// q-slot of qkv (cols h*32..h*32+31 of rows of this bh). q is dead after.
// ---------------------------------------------------------------------------
__global__ __launch_bounds__(256) void k_attn_out(
    float* __restrict__ qkv, const float* __restrict__ kvbuf,
    const float* __restrict__ ksumbuf) {
  const int bh = blockIdx.y;
  const int b = bh >> 3, h = bh & 7;
  const int i0 = blockIdx.x * 64;
  const int tid = threadIdx.x;
  __shared__ float kv_s[1024];
  __shared__ float ksum_s[32];
  __shared__ float q_s[256];

  for (int p = tid; p < 1024; p += 256) kv_s[p] = kvbuf[bh * 1024 + p];
  if (tid < 32) ksum_s[tid] = ksumbuf[bh * 32 + tid];

  const int r = tid >> 5;   // row within pass (0..7)
  const int d = tid & 31;

  for (int pass = 0; pass < 8; ++pass) {
    const int i = i0 + pass * 8;
    __syncthreads();
    q_s[tid] =
        qkv[((size_t)(b * N_ + i + (tid >> 5))) * QKVC + h * HD_ + (tid & 31)];
    __syncthreads();
    float s = 0.f, zden = 0.f;
#pragma unroll
    for (int cc = 0; cc < 32; ++cc) {
      const float qv = q_s[r * 32 + cc];
      s += qv * kv_s[cc * 32 + d];
      zden += qv * ksum_s[cc];
    }
    const float z = 1.f / (zden + EPS_);
    // overwrite q-slot with attention output
    qkv[((size_t)(b * N_ + i + r)) * QKVC + h * HD_ + d] = s * z;
  }
}

// ---------------------------------------------------------------------------
// K5: depthwise 5x5 SAME conv on v; accumulates into the q-slot (attn).
// ---------------------------------------------------------------------------
__global__ __launch_bounds__(256) void k_dwconv(float* __restrict__ qkv,
                                                const float* __restrict__ dwc_w,
                                                const float* __restrict__ dwc_b) {
  const int bh = blockIdx.y;
  const int b = bh >> 3, h = bh & 7;
  const int n = blockIdx.x * 256 + threadIdx.x;
  const int i = n >> 6, j = n & 63;
  __shared__ float w_s[32 * 25];
  __shared__ float b_s[32];
  for (int p = threadIdx.x; p < 800; p += 256) w_s[p] = dwc_w[p];
  if (threadIdx.x < 32) b_s[threadIdx.x] = dwc_b[threadIdx.x];
  __syncthreads();

  float fm[32];
#pragma unroll
  for (int cc = 0; cc < 32; ++cc) fm[cc] = b_s[cc];

#pragma unroll
  for (int ki = 0; ki < 5; ++ki) {
    const int ii = i + ki - 2;
    if (ii < 0 || ii >= 64) continue;
#pragma unroll
    for (int kj = 0; kj < 5; ++kj) {
      const int jj = j + kj - 2;
      if (jj < 0 || jj >= 64) continue;
      const float* vrow =
          &qkv[((size_t)(b * N_ + ii * 64 + jj)) * QKVC + 2 * C_ + h * HD_];
#pragma unroll
      for (int cc = 0; cc < 32; ++cc)
        fm[cc] += vrow[cc] * w_s[cc * 25 + ki * 5 + kj];
    }
  }
  float* arow = &qkv[((size_t)(b * N_ + n)) * QKVC + h * HD_];
#pragma unroll
  for (int cc = 0; cc < 32; ++cc) arow[cc] += fm[cc];
}

// ---------------------------------------------------------------------------
// K6: out = attn @ proj_w^T + proj_b, A read from qkv q-slot (stride 768),
// stored transposed to [B, C, N].
// ---------------------------------------------------------------------------
__global__ __launch_bounds__(256) void k_proj_gemm(
    const float* __restrict__ qkv, const float* __restrict__ w,
    const float* __restrict__ bias, float* __restrict__ out) {
  __shared__ float As[16][64];
  __shared__ float Bs[16][64];
  const int m0 = blockIdx.x * 64;
  const int b = m0 / N_;
  const int n0 = m0 % N_;
  const int col0 = blockIdx.y * 64;
  const int tid = threadIdx.x;
  const int ty = tid >> 4, tx = tid & 15;

  const int a_m = tid >> 2;        // 0..63
  const int a_k = (tid & 3) * 4;   // 0..12
  const int b_col = tid >> 2;
  const int b_k = (tid & 3) * 4;

  float acc[4][4] = {};

  for (int k0 = 0; k0 < C_; k0 += 16) {
    float4 av = *reinterpret_cast<const float4*>(
        &qkv[(size_t)(m0 + a_m) * QKVC + k0 + a_k]);
    As[a_k + 0][a_m] = av.x;
    As[a_k + 1][a_m] = av.y;
    As[a_k + 2][a_m] = av.z;
    As[a_k + 3][a_m] = av.w;
    float4 bv = *reinterpret_cast<const float4*>(
        &w[(size_t)(col0 + b_col) * C_ + k0 + b_k]);
    Bs[b_k + 0][b_col] = bv.x;
    Bs[b_k + 1][b_col] = bv.y;
    Bs[b_k + 2][b_col] = bv.z;
    Bs[b_k + 3][b_col] = bv.w;
    __syncthreads();
#pragma unroll
    for (int kk = 0; kk < 16; ++kk) {
      float4 a = *reinterpret_cast<const float4*>(&As[kk][ty * 4]);
      float4 bq = *reinterpret_cast<const float4*>(&Bs[kk][tx * 4]);
      float ar[4] = {a.x, a.y, a.z, a.w};
      float br[4] = {bq.x, bq.y, bq.z, bq.w};
#pragma unroll
      for (int i = 0; i < 4; ++i)
#pragma unroll
        for (int j = 0; j < 4; ++j) acc[i][j] += ar[i] * br[j];
    }
    __syncthreads();
  }

#pragma unroll
  for (int j = 0; j < 4; ++j) {
    const int colg = col0 + tx * 4 + j;
    const float bb = bias[colg];
    float4 o = make_float4(acc[0][j] + bb, acc[1][j] + bb, acc[2][j] + bb,
                           acc[3][j] + bb);
    *reinterpret_cast<float4*>(
        &out[((size_t)(b * C_ + colg)) * N_ + n0 + ty * 4]) = o;
  }
}

// ---------------------------------------------------------------------------
extern "C" void kernel_launch(void* const* d_in, const int* in_sizes, int n_in,
                              void* d_out, int out_size, void* d_ws,
                              size_t ws_size, hipStream_t stream) {
  (void)in_sizes; (void)n_in; (void)out_size; (void)ws_size;
  const float* x      = (const float*)d_in[0];
  const float* qkv_w  = (const float*)d_in[1];
  const float* qkv_b  = (const float*)d_in[2];
  const float* proj_w = (const float*)d_in[3];
  const float* proj_b = (const float*)d_in[4];
  const float* dwc_w  = (const float*)d_in[5];
  const float* dwc_b  = (const float*)d_in[6];
  const float* scale  = (const float*)d_in[7];
  float* out = (float*)d_out;

  float* qkv_buf  = (float*)d_ws;                      // [M, 768]  201.3 MB
  float* kv_buf   = qkv_buf + (size_t)M_ * QKVC;       // [128, 32, 32]
  float* ksum_buf = kv_buf + 128 * 1024;               // [128, 32]

  k_qkv_gemm<<<dim3(M_ / 64, QKVC / 64), 256, 0, stream>>>(x, qkv_w, qkv_b,
                                                           qkv_buf);
  k_focus<<<M_, 256, 0, stream>>>(qkv_buf, scale);
  k_kv<<<128, 256, 0, stream>>>(qkv_buf, kv_buf, ksum_buf);
  k_attn_out<<<dim3(N_ / 64, 128), 256, 0, stream>>>(qkv_buf, kv_buf, ksum_buf);
  k_dwconv<<<dim3(N_ / 256, 128), 256, 0, stream>>>(qkv_buf, dwc_w, dwc_b);
  k_proj_gemm<<<dim3(M_ / 64, C_ / 64), 256, 0, stream>>>(qkv_buf, proj_w,
                                                          proj_b, out);
}

// Round 4
// 906.798 us; speedup vs baseline: 1.2264x; 1.2264x over previous
//
#include <hip/hip_runtime.h>
#include <cmath>

#define B_   16
#define C_   256
#define HW_  64
#define N_   4096          // 64*64
#define NH_  8
#define HD_  32
#define M_   (B_ * N_)     // 65536
#define QKVC (3 * C_)      // 768
#define EPS_ 1e-6f

typedef short bf16x8 __attribute__((ext_vector_type(8)));
typedef float f32x4 __attribute__((ext_vector_type(4)));

__device__ __forceinline__ float b2f(unsigned short u) {
  union { unsigned int i; float f; } v;
  v.i = ((unsigned int)u) << 16;
  return v.f;
}
__device__ __forceinline__ unsigned short f2b(float f) {
  union { float f; unsigned int i; } v;
  v.f = f;
  unsigned int r = v.i + 0x7FFFu + ((v.i >> 16) & 1u);  // RNE
  return (unsigned short)(r >> 16);
}
__device__ __forceinline__ void gload_lds16(const void* g, void* l) {
  __builtin_amdgcn_global_load_lds(
      (const __attribute__((address_space(1))) void*)g,
      (__attribute__((address_space(3))) void*)l, 16, 0, 0);
}

// ---------------------------------------------------------------------------
// K0a: transpose-cast x [b][c][n] f32 -> xT [b][n][c] bf16
// ---------------------------------------------------------------------------
__global__ __launch_bounds__(256) void k_cast_x(const float* __restrict__ x,
                                                unsigned short* __restrict__ xT) {
  __shared__ float t[32][33];
  const int n0 = blockIdx.x * 32, c0 = blockIdx.y * 32, b = blockIdx.z;
  const int tid = threadIdx.x;
  const int r = tid >> 3, g = (tid & 7) * 4;
  float4 v = *reinterpret_cast<const float4*>(
      &x[((size_t)(b * C_ + c0 + r)) * N_ + n0 + g]);
  t[r][g + 0] = v.x; t[r][g + 1] = v.y; t[r][g + 2] = v.z; t[r][g + 3] = v.w;
  __syncthreads();
  ushort4 o;
  o.x = f2b(t[g + 0][r]); o.y = f2b(t[g + 1][r]);
  o.z = f2b(t[g + 2][r]); o.w = f2b(t[g + 3][r]);
  *reinterpret_cast<ushort4*>(&xT[((size_t)(b * N_ + n0 + r)) * C_ + c0 + g]) = o;
}

// ---------------------------------------------------------------------------
// K0b: cast qkv_w (768x256) and proj_w (256x256) to bf16 (contiguous dst)
// ---------------------------------------------------------------------------
__global__ __launch_bounds__(256) void k_cast_w(const float* __restrict__ w1,
                                                const float* __restrict__ w2,
                                                unsigned short* __restrict__ dst) {
  const int g4 = (blockIdx.x * 256 + threadIdx.x) * 4;  // < 262144
  float4 v;
  if (g4 < 196608) v = *reinterpret_cast<const float4*>(w1 + g4);
  else             v = *reinterpret_cast<const float4*>(w2 + (g4 - 196608));
  ushort4 o;
  o.x = f2b(v.x); o.y = f2b(v.y); o.z = f2b(v.z); o.w = f2b(v.w);
  *reinterpret_cast<ushort4*>(dst + g4) = o;
}

// ---------------------------------------------------------------------------
// K1/K6: bf16 MFMA GEMM, 128x128 tile, BK=64, 4 waves (2x2 of 64x64),
// global_load_lds staging with XOR slot-swizzle (slot ^= row&7).
// A: [M][K] bf16 row-major, row stride LDA elements. W: [col][K=256] bf16.
// OUTMODE 0: bf16 row-major [M][768] + bias ; OUTMODE 1: f32 [B][256][4096]
// transposed store + bias.
// ---------------------------------------------------------------------------
template <int LDA, int OUTMODE>
__global__ __launch_bounds__(256) void k_gemm(
    const unsigned short* __restrict__ A, const unsigned short* __restrict__ W,
    const float* __restrict__ bias, void* __restrict__ outp) {
  __shared__ unsigned short As[128 * 64];
  __shared__ unsigned short Bs[128 * 64];
  const int tid = threadIdx.x;
  const int wid = tid >> 6, lane = tid & 63;
  const int m0 = blockIdx.x * 128;
  const int col0 = blockIdx.y * 128;
  const int wr = wid >> 1, wc = wid & 1;

  const int lrow = lane >> 3;
  const int sl = (lane & 7) ^ (lrow & 7);  // logical 16B-slot this lane fetches

  f32x4 acc[4][4];
#pragma unroll
  for (int i = 0; i < 4; ++i)
#pragma unroll
    for (int j = 0; j < 4; ++j) acc[i][j] = (f32x4){0.f, 0.f, 0.f, 0.f};

  for (int kt = 0; kt < 4; ++kt) {
    const int k0 = kt * 64;
#pragma unroll
    for (int q = 0; q < 4; ++q) {
      const int chunk = wid * 4 + q;          // 0..15, 8 rows each
      const int row = chunk * 8 + lrow;       // 0..127
      gload_lds16(A + (size_t)(m0 + row) * LDA + k0 + sl * 8, &As[chunk * 512]);
      gload_lds16(W + (size_t)(col0 + row) * 256 + k0 + sl * 8, &Bs[chunk * 512]);
    }
    __syncthreads();  // drains vmcnt -> staged tiles visible

    bf16x8 fa[2][4], fb[2][4];
#pragma unroll
    for (int i = 0; i < 4; ++i) {
      const int ra = wr * 64 + i * 16 + (lane & 15);
      const int rb = wc * 64 + i * 16 + (lane & 15);
#pragma unroll
      for (int ks = 0; ks < 2; ++ks) {
        const int s = ks * 4 + (lane >> 4);
        fa[ks][i] = *reinterpret_cast<const bf16x8*>(
            &As[ra * 64 + ((s ^ (ra & 7)) * 8)]);
        fb[ks][i] = *reinterpret_cast<const bf16x8*>(
            &Bs[rb * 64 + ((s ^ (rb & 7)) * 8)]);
      }
    }
#pragma unroll
    for (int i = 0; i < 4; ++i)
#pragma unroll
      for (int j = 0; j < 4; ++j) {
        acc[i][j] = __builtin_amdgcn_mfma_f32_16x16x32_bf16(fa[0][i], fb[0][j],
                                                            acc[i][j], 0, 0, 0);
        acc[i][j] = __builtin_amdgcn_mfma_f32_16x16x32_bf16(fa[1][i], fb[1][j],
                                                            acc[i][j], 0, 0, 0);
      }
    __syncthreads();
  }

  // C/D layout: col = lane&15, row = (lane>>4)*4 + reg   [m89/m91]
  if (OUTMODE == 0) {
    unsigned short* O = (unsigned short*)outp;
#pragma unroll
    for (int j = 0; j < 4; ++j) {
      const int colg = col0 + wc * 64 + j * 16 + (lane & 15);
      const float bb = bias[colg];
#pragma unroll
      for (int i = 0; i < 4; ++i) {
        const int mrow = m0 + wr * 64 + i * 16 + ((lane >> 4) << 2);
#pragma unroll
        for (int r = 0; r < 4; ++r)
          O[(size_t)(mrow + r) * QKVC + colg] = f2b(acc[i][j][r] + bb);
      }
    }
  } else {
    float* O = (float*)outp;
    const int b = m0 >> 12;
    const int nb0 = (m0 & 4095) + wr * 64;
#pragma unroll
    for (int j = 0; j < 4; ++j) {
      const int colg = col0 + wc * 64 + j * 16 + (lane & 15);
      const float bb = bias[colg];
#pragma unroll
      for (int i = 0; i < 4; ++i) {
        const int nb = nb0 + i * 16 + ((lane >> 4) << 2);
        f32x4 o = acc[i][j];
        o += bb;
        *reinterpret_cast<f32x4*>(&O[((size_t)(b * C_ + colg)) * N_ + nb]) = o;
      }
    }
  }
}

// ---------------------------------------------------------------------------
// K2: focusing feature map, in-place on q,k halves of qkv (bf16).
// ---------------------------------------------------------------------------
__global__ __launch_bounds__(256) void k_focus(unsigned short* __restrict__ qkv,
                                               const float* __restrict__ scale) {
  const int t = blockIdx.x;
  const int c = threadIdx.x;
  const size_t base = (size_t)t * QKVC;
  const float sc = log1pf(expf(scale[c]));  // softplus

  float q = b2f(qkv[base + c]);
  float k = b2f(qkv[base + C_ + c]);
  q = fmaxf(q, 0.f) + EPS_;
  k = fmaxf(k, 0.f) + EPS_;
  q /= sc;
  k /= sc;
  const float q3 = q * q * q;
  const float k3 = k * k * k;

  float v0 = q * q, v1 = q3 * q3, v2 = k * k, v3 = k3 * k3;
#pragma unroll
  for (int off = 32; off > 0; off >>= 1) {
    v0 += __shfl_down(v0, off);
    v1 += __shfl_down(v1, off);
    v2 += __shfl_down(v2, off);
    v3 += __shfl_down(v3, off);
  }
  __shared__ float red[4][4];
  const int wave = threadIdx.x >> 6;
  const int lane = threadIdx.x & 63;
  if (lane == 0) {
    red[wave][0] = v0; red[wave][1] = v1;
    red[wave][2] = v2; red[wave][3] = v3;
  }
  __syncthreads();
  const float sq2 = red[0][0] + red[1][0] + red[2][0] + red[3][0];
  const float sq6 = red[0][1] + red[1][1] + red[2][1] + red[3][1];
  const float sk2 = red[0][2] + red[1][2] + red[2][2] + red[3][2];
  const float sk6 = red[0][3] + red[1][3] + red[2][3] + red[3][3];

  qkv[base + c] = f2b(q3 * (sqrtf(sq2) / sqrtf(sq6)));
  qkv[base + C_ + c] = f2b(k3 * (sqrtf(sk2) / sqrtf(sk6)));
}

// ---------------------------------------------------------------------------
// K3: kv partials per (bh, chunk of 512 rows): kvp[c][d], ksump[c]
// ---------------------------------------------------------------------------
__global__ __launch_bounds__(256) void k_kv_part(
    const unsigned short* __restrict__ qkv, float* __restrict__ kvp,
    float* __restrict__ ksp) {
  const int bh = blockIdx.x;
  const int chunk = blockIdx.y;
  const int b = bh >> 3, h = bh & 7;
  const int tid = threadIdx.x;
  __shared__ float ks[16][32];
  __shared__ float vs[16][32];
  const int c = tid >> 3;
  const int d0 = (tid & 7) * 4;
  float a0 = 0.f, a1 = 0.f, a2 = 0.f, a3 = 0.f;
  float ksum_acc = 0.f;

  const int sel = tid >> 7;            // 0: k-tile, 1: v-tile
  const int f = (tid & 127) * 4;
  const int jj_l = f >> 5, cc_l = f & 31;

  const int j_end = chunk * 512 + 512;
  for (int j0 = chunk * 512; j0 < j_end; j0 += 16) {
    __syncthreads();
    {
      const size_t rb = ((size_t)(b * N_ + j0 + jj_l)) * QKVC +
                        (sel ? 2 * C_ : C_) + h * HD_ + cc_l;
      uint2 u = *reinterpret_cast<const uint2*>(qkv + rb);
      float* dst = sel ? &vs[jj_l][cc_l] : &ks[jj_l][cc_l];
      dst[0] = b2f((unsigned short)(u.x & 0xffff));
      dst[1] = b2f((unsigned short)(u.x >> 16));
      dst[2] = b2f((unsigned short)(u.y & 0xffff));
      dst[3] = b2f((unsigned short)(u.y >> 16));
    }
    __syncthreads();
#pragma unroll
    for (int jj = 0; jj < 16; ++jj) {
      const float kc = ks[jj][c];
      a0 += kc * vs[jj][d0 + 0];
      a1 += kc * vs[jj][d0 + 1];
      a2 += kc * vs[jj][d0 + 2];
      a3 += kc * vs[jj][d0 + 3];
    }
    if (tid < 32) {
#pragma unroll
      for (int jj = 0; jj < 16; ++jj) ksum_acc += ks[jj][tid];
    }
  }
  float* kvo = kvp + ((size_t)chunk * 128 + bh) * 1024 + c * 32 + d0;
  kvo[0] = a0; kvo[1] = a1; kvo[2] = a2; kvo[3] = a3;
  if (tid < 32) ksp[((size_t)chunk * 128 + bh) * 32 + tid] = ksum_acc;
}

// ---------------------------------------------------------------------------
// K3b: reduce 8 chunks -> kv_buf [128][1024], ksum_buf [128][32]
// ---------------------------------------------------------------------------
__global__ __launch_bounds__(256) void k_kv_reduce(
    const float* __restrict__ kvp, const float* __restrict__ ksp,
    float* __restrict__ kv, float* __restrict__ ksum) {
  const int bh = blockIdx.x;
  for (int p = threadIdx.x; p < 1024; p += 256) {
    float s = 0.f;
#pragma unroll
    for (int ch = 0; ch < 8; ++ch) s += kvp[((size_t)ch * 128 + bh) * 1024 + p];
    kv[bh * 1024 + p] = s;
  }
  if (threadIdx.x < 32) {
    float s = 0.f;
#pragma unroll
    for (int ch = 0; ch < 8; ++ch)
      s += ksp[((size_t)ch * 128 + bh) * 32 + threadIdx.x];
    ksum[bh * 32 + threadIdx.x] = s;
  }
}

// ---------------------------------------------------------------------------
// K4: fused attn-out + depthwise 5x5 conv; writes bf16 into q-slot of qkv.
// ---------------------------------------------------------------------------
__global__ __launch_bounds__(256) void k_attn_conv(
    unsigned short* __restrict__ qkv, const float* __restrict__ kv,
    const float* __restrict__ ksum, const float* __restrict__ dwc_w,
    const float* __restrict__ dwc_b) {
  const int bh = blockIdx.y;
  const int b = bh >> 3, h = bh & 7;
  const int tid = threadIdx.x;
  const int n = blockIdx.x * 256 + tid;
  const int i = n >> 6, j = n & 63;
  __shared__ float kv_s[1024];
  __shared__ float ksum_s[32];
  __shared__ float w_s[800];   // [tap][channel]
  __shared__ float b_s[32];
  for (int p = tid; p < 1024; p += 256) kv_s[p] = kv[bh * 1024 + p];
  if (tid < 32) ksum_s[tid] = ksum[bh * 32 + tid];
  for (int p = tid; p < 800; p += 256)
    w_s[p] = dwc_w[(p & 31) * 25 + (p >> 5)];
  if (tid < 32) b_s[tid] = dwc_b[tid];
  __syncthreads();

  // ---- attention: out_d = z * sum_c q_c kv[c][d]
  const unsigned short* qrow = qkv + ((size_t)(b * N_ + n)) * QKVC + h * HD_;
  float qf[32];
  {
    union { uint4 u[4]; unsigned short s[32]; } ld;
#pragma unroll
    for (int q = 0; q < 4; ++q)
      ld.u[q] = *reinterpret_cast<const uint4*>(qrow + q * 8);
#pragma unroll
    for (int c = 0; c < 32; ++c) qf[c] = b2f(ld.s[c]);
  }
  float sacc[32];
#pragma unroll
  for (int d = 0; d < 32; ++d) sacc[d] = 0.f;
  float zden = 0.f;
#pragma unroll
  for (int c = 0; c < 32; ++c) {
    const float qc = qf[c];
    zden += qc * ksum_s[c];
#pragma unroll
    for (int d = 0; d < 32; ++d) sacc[d] += qc * kv_s[c * 32 + d];
  }
  const float z = 1.f / (zden + EPS_);

  // ---- depthwise conv on v
  float fm[32];
#pragma unroll
  for (int c = 0; c < 32; ++c) fm[c] = b_s[c];
  for (int ki = 0; ki < 5; ++ki) {
    const int ii = i + ki - 2;
    if (ii < 0 || ii >= 64) continue;
    for (int kj = 0; kj < 5; ++kj) {
      const int jj = j + kj - 2;
      if (jj < 0 || jj >= 64) continue;
      const unsigned short* vrow =
          qkv + ((size_t)(b * N_ + ii * 64 + jj)) * QKVC + 2 * C_ + h * HD_;
      union { uint4 u[4]; unsigned short s[32]; } ld;
#pragma unroll
      for (int q = 0; q < 4; ++q)
        ld.u[q] = *reinterpret_cast<const uint4*>(vrow + q * 8);
      const int t = ki * 5 + kj;
#pragma unroll
      for (int c = 0; c < 32; ++c) fm[c] += b2f(ld.s[c]) * w_s[t * 32 + c];
    }
  }

  union { uint4 u[4]; unsigned short s[32]; } st;
#pragma unroll
  for (int c = 0; c < 32; ++c) st.s[c] = f2b(z * sacc[c] + fm[c]);
  unsigned short* orow = qkv + ((size_t)(b * N_ + n)) * QKVC + h * HD_;
#pragma unroll
  for (int q = 0; q < 4; ++q)
    *reinterpret_cast<uint4*>(orow + q * 8) = st.u[q];
}

// ---------------------------------------------------------------------------
extern "C" void kernel_launch(void* const* d_in, const int* in_sizes, int n_in,
                              void* d_out, int out_size, void* d_ws,
                              size_t ws_size, hipStream_t stream) {
  (void)in_sizes; (void)n_in; (void)out_size; (void)ws_size;
  const float* x      = (const float*)d_in[0];
  const float* qkv_w  = (const float*)d_in[1];
  const float* qkv_b  = (const float*)d_in[2];
  const float* proj_w = (const float*)d_in[3];
  const float* proj_b = (const float*)d_in[4];
  const float* dwc_w  = (const float*)d_in[5];
  const float* dwc_b  = (const float*)d_in[6];
  const float* scale  = (const float*)d_in[7];
  float* out = (float*)d_out;

  char* w = (char*)d_ws;
  unsigned short* xT   = (unsigned short*)w; w += (size_t)M_ * C_ * 2;     // 33.6MB
  unsigned short* qkvb = (unsigned short*)w; w += (size_t)M_ * QKVC * 2;   // 100.7MB
  // FIX (round 3 NaN): reserve space for BOTH weight matrices. Previously wp
  // aliased kvp — k_kv_part overwrote proj weights with f32 partials whose
  // low-mantissa halves decode as bf16 inf/NaN -> MFMA inf*0 -> NaN.
  unsigned short* wq   = (unsigned short*)w; w += (size_t)(QKVC + C_) * C_ * 2;
  unsigned short* wp   = wq + (size_t)QKVC * C_;
  float* kvp   = (float*)w;                  w += (size_t)8 * 128 * 1024 * 4;
  float* ksp   = (float*)w;                  w += (size_t)8 * 128 * 32 * 4;
  float* kvb   = (float*)w;                  w += 128 * 1024 * 4;
  float* ksumb = (float*)w;                  w += 128 * 32 * 4;

  k_cast_x<<<dim3(N_ / 32, C_ / 32, B_), 256, 0, stream>>>(x, xT);
  k_cast_w<<<256, 256, 0, stream>>>(qkv_w, proj_w, wq);
  k_gemm<256, 0><<<dim3(M_ / 128, QKVC / 128), 256, 0, stream>>>(
      xT, wq, qkv_b, (void*)qkvb);
  k_focus<<<M_, 256, 0, stream>>>(qkvb, scale);
  k_kv_part<<<dim3(128, 8), 256, 0, stream>>>(qkvb, kvp, ksp);
  k_kv_reduce<<<128, 256, 0, stream>>>(kvp, ksp, kvb, ksumb);
  k_attn_conv<<<dim3(N_ / 256, 128), 256, 0, stream>>>(qkvb, kvb, ksumb,
                                                       dwc_w, dwc_b);
  k_gemm<768, 1><<<dim3(M_ / 128, C_ / 128), 256, 0, stream>>>(
      qkvb, wp, proj_b, (void*)out);
}

// Round 5
// 570.112 us; speedup vs baseline: 1.9507x; 1.5906x over previous
//
#include <hip/hip_runtime.h>
#include <cmath>

#define B_   16
#define C_   256
#define HW_  64
#define N_   4096          // 64*64
#define NH_  8
#define HD_  32
#define M_   (B_ * N_)     // 65536
#define QKVC (3 * C_)      // 768
#define EPS_ 1e-6f

typedef short bf16x8 __attribute__((ext_vector_type(8)));
typedef float f32x4 __attribute__((ext_vector_type(4)));

__device__ __forceinline__ float b2f(unsigned short u) {
  union { unsigned int i; float f; } v;
  v.i = ((unsigned int)u) << 16;
  return v.f;
}
__device__ __forceinline__ unsigned short f2b(float f) {
  union { float f; unsigned int i; } v;
  v.f = f;
  unsigned int r = v.i + 0x7FFFu + ((v.i >> 16) & 1u);  // RNE
  return (unsigned short)(r >> 16);
}
__device__ __forceinline__ void gload_lds16(const void* g, void* l) {
  __builtin_amdgcn_global_load_lds(
      (const __attribute__((address_space(1))) void*)g,
      (__attribute__((address_space(3))) void*)l, 16, 0, 0);
}

// ---------------------------------------------------------------------------
// K0a: transpose-cast x [b][c][n] f32 -> xT [b][n][c] bf16
// ---------------------------------------------------------------------------
__global__ __launch_bounds__(256) void k_cast_x(const float* __restrict__ x,
                                                unsigned short* __restrict__ xT) {
  __shared__ float t[32][33];
  const int n0 = blockIdx.x * 32, c0 = blockIdx.y * 32, b = blockIdx.z;
  const int tid = threadIdx.x;
  const int r = tid >> 3, g = (tid & 7) * 4;
  float4 v = *reinterpret_cast<const float4*>(
      &x[((size_t)(b * C_ + c0 + r)) * N_ + n0 + g]);
  t[r][g + 0] = v.x; t[r][g + 1] = v.y; t[r][g + 2] = v.z; t[r][g + 3] = v.w;
  __syncthreads();
  ushort4 o;
  o.x = f2b(t[g + 0][r]); o.y = f2b(t[g + 1][r]);
  o.z = f2b(t[g + 2][r]); o.w = f2b(t[g + 3][r]);
  *reinterpret_cast<ushort4*>(&xT[((size_t)(b * N_ + n0 + r)) * C_ + c0 + g]) = o;
}

// ---------------------------------------------------------------------------
// K0b: cast qkv_w (768x256) and proj_w (256x256) to bf16 (contiguous dst)
// ---------------------------------------------------------------------------
__global__ __launch_bounds__(256) void k_cast_w(const float* __restrict__ w1,
                                                const float* __restrict__ w2,
                                                unsigned short* __restrict__ dst) {
  const int g4 = (blockIdx.x * 256 + threadIdx.x) * 4;  // < 262144
  float4 v;
  if (g4 < 196608) v = *reinterpret_cast<const float4*>(w1 + g4);
  else             v = *reinterpret_cast<const float4*>(w2 + (g4 - 196608));
  ushort4 o;
  o.x = f2b(v.x); o.y = f2b(v.y); o.z = f2b(v.z); o.w = f2b(v.w);
  *reinterpret_cast<ushort4*>(dst + g4) = o;
}

// ---------------------------------------------------------------------------
// K1/K6: bf16 MFMA GEMM, 128x128 tile, BK=64, 4 waves (2x2 of 64x64),
// global_load_lds staging with XOR slot-swizzle (slot ^= row&7).
// ---------------------------------------------------------------------------
template <int LDA, int OUTMODE>
__global__ __launch_bounds__(256) void k_gemm(
    const unsigned short* __restrict__ A, const unsigned short* __restrict__ W,
    const float* __restrict__ bias, void* __restrict__ outp) {
  __shared__ unsigned short As[128 * 64];
  __shared__ unsigned short Bs[128 * 64];
  const int tid = threadIdx.x;
  const int wid = tid >> 6, lane = tid & 63;
  const int m0 = blockIdx.x * 128;
  const int col0 = blockIdx.y * 128;
  const int wr = wid >> 1, wc = wid & 1;

  const int lrow = lane >> 3;
  const int sl = (lane & 7) ^ (lrow & 7);  // logical 16B-slot this lane fetches

  f32x4 acc[4][4];
#pragma unroll
  for (int i = 0; i < 4; ++i)
#pragma unroll
    for (int j = 0; j < 4; ++j) acc[i][j] = (f32x4){0.f, 0.f, 0.f, 0.f};

  for (int kt = 0; kt < 4; ++kt) {
    const int k0 = kt * 64;
#pragma unroll
    for (int q = 0; q < 4; ++q) {
      const int chunk = wid * 4 + q;          // 0..15, 8 rows each
      const int row = chunk * 8 + lrow;       // 0..127
      gload_lds16(A + (size_t)(m0 + row) * LDA + k0 + sl * 8, &As[chunk * 512]);
      gload_lds16(W + (size_t)(col0 + row) * 256 + k0 + sl * 8, &Bs[chunk * 512]);
    }
    __syncthreads();  // drains vmcnt -> staged tiles visible

    bf16x8 fa[2][4], fb[2][4];
#pragma unroll
    for (int i = 0; i < 4; ++i) {
      const int ra = wr * 64 + i * 16 + (lane & 15);
      const int rb = wc * 64 + i * 16 + (lane & 15);
#pragma unroll
      for (int ks = 0; ks < 2; ++ks) {
        const int s = ks * 4 + (lane >> 4);
        fa[ks][i] = *reinterpret_cast<const bf16x8*>(
            &As[ra * 64 + ((s ^ (ra & 7)) * 8)]);
        fb[ks][i] = *reinterpret_cast<const bf16x8*>(
            &Bs[rb * 64 + ((s ^ (rb & 7)) * 8)]);
      }
    }
#pragma unroll
    for (int i = 0; i < 4; ++i)
#pragma unroll
      for (int j = 0; j < 4; ++j) {
        acc[i][j] = __builtin_amdgcn_mfma_f32_16x16x32_bf16(fa[0][i], fb[0][j],
                                                            acc[i][j], 0, 0, 0);
        acc[i][j] = __builtin_amdgcn_mfma_f32_16x16x32_bf16(fa[1][i], fb[1][j],
                                                            acc[i][j], 0, 0, 0);
      }
    __syncthreads();
  }

  // C/D layout: col = lane&15, row = (lane>>4)*4 + reg   [m89/m91]
  if (OUTMODE == 0) {
    unsigned short* O = (unsigned short*)outp;
#pragma unroll
    for (int j = 0; j < 4; ++j) {
      const int colg = col0 + wc * 64 + j * 16 + (lane & 15);
      const float bb = bias[colg];
#pragma unroll
      for (int i = 0; i < 4; ++i) {
        const int mrow = m0 + wr * 64 + i * 16 + ((lane >> 4) << 2);
#pragma unroll
        for (int r = 0; r < 4; ++r)
          O[(size_t)(mrow + r) * QKVC + colg] = f2b(acc[i][j][r] + bb);
      }
    }
  } else {
    float* O = (float*)outp;
    const int b = m0 >> 12;
    const int nb0 = (m0 & 4095) + wr * 64;
#pragma unroll
    for (int j = 0; j < 4; ++j) {
      const int colg = col0 + wc * 64 + j * 16 + (lane & 15);
      const float bb = bias[colg];
#pragma unroll
      for (int i = 0; i < 4; ++i) {
        const int nb = nb0 + i * 16 + ((lane >> 4) << 2);
        f32x4 o = acc[i][j];
        o += bb;
        *reinterpret_cast<f32x4*>(&O[((size_t)(b * C_ + colg)) * N_ + nb]) = o;
      }
    }
  }
}

// ---------------------------------------------------------------------------
// K2: focusing feature map, in-place on q,k halves of qkv (bf16).
// ---------------------------------------------------------------------------
__global__ __launch_bounds__(256) void k_focus(unsigned short* __restrict__ qkv,
                                               const float* __restrict__ scale) {
  const int t = blockIdx.x;
  const int c = threadIdx.x;
  const size_t base = (size_t)t * QKVC;
  const float sc = log1pf(expf(scale[c]));  // softplus

  float q = b2f(qkv[base + c]);
  float k = b2f(qkv[base + C_ + c]);
  q = fmaxf(q, 0.f) + EPS_;
  k = fmaxf(k, 0.f) + EPS_;
  q /= sc;
  k /= sc;
  const float q3 = q * q * q;
  const float k3 = k * k * k;

  float v0 = q * q, v1 = q3 * q3, v2 = k * k, v3 = k3 * k3;
#pragma unroll
  for (int off = 32; off > 0; off >>= 1) {
    v0 += __shfl_down(v0, off);
    v1 += __shfl_down(v1, off);
    v2 += __shfl_down(v2, off);
    v3 += __shfl_down(v3, off);
  }
  __shared__ float red[4][4];
  const int wave = threadIdx.x >> 6;
  const int lane = threadIdx.x & 63;
  if (lane == 0) {
    red[wave][0] = v0; red[wave][1] = v1;
    red[wave][2] = v2; red[wave][3] = v3;
  }
  __syncthreads();
  const float sq2 = red[0][0] + red[1][0] + red[2][0] + red[3][0];
  const float sq6 = red[0][1] + red[1][1] + red[2][1] + red[3][1];
  const float sk2 = red[0][2] + red[1][2] + red[2][2] + red[3][2];
  const float sk6 = red[0][3] + red[1][3] + red[2][3] + red[3][3];

  qkv[base + c] = f2b(q3 * (sqrtf(sq2) / sqrtf(sq6)));
  qkv[base + C_ + c] = f2b(k3 * (sqrtf(sk2) / sqrtf(sk6)));
}

// ---------------------------------------------------------------------------
// K3: kv partials per (bh, chunk of 512 rows): kvp[c][d], ksump[c]
// ---------------------------------------------------------------------------
__global__ __launch_bounds__(256) void k_kv_part(
    const unsigned short* __restrict__ qkv, float* __restrict__ kvp,
    float* __restrict__ ksp) {
  const int bh = blockIdx.x;
  const int chunk = blockIdx.y;
  const int b = bh >> 3, h = bh & 7;
  const int tid = threadIdx.x;
  __shared__ float ks[16][32];
  __shared__ float vs[16][32];
  const int c = tid >> 3;
  const int d0 = (tid & 7) * 4;
  float a0 = 0.f, a1 = 0.f, a2 = 0.f, a3 = 0.f;
  float ksum_acc = 0.f;

  const int sel = tid >> 7;            // 0: k-tile, 1: v-tile
  const int f = (tid & 127) * 4;
  const int jj_l = f >> 5, cc_l = f & 31;

  const int j_end = chunk * 512 + 512;
  for (int j0 = chunk * 512; j0 < j_end; j0 += 16) {
    __syncthreads();
    {
      const size_t rb = ((size_t)(b * N_ + j0 + jj_l)) * QKVC +
                        (sel ? 2 * C_ : C_) + h * HD_ + cc_l;
      uint2 u = *reinterpret_cast<const uint2*>(qkv + rb);
      float* dst = sel ? &vs[jj_l][cc_l] : &ks[jj_l][cc_l];
      dst[0] = b2f((unsigned short)(u.x & 0xffff));
      dst[1] = b2f((unsigned short)(u.x >> 16));
      dst[2] = b2f((unsigned short)(u.y & 0xffff));
      dst[3] = b2f((unsigned short)(u.y >> 16));
    }
    __syncthreads();
#pragma unroll
    for (int jj = 0; jj < 16; ++jj) {
      const float kc = ks[jj][c];
      a0 += kc * vs[jj][d0 + 0];
      a1 += kc * vs[jj][d0 + 1];
      a2 += kc * vs[jj][d0 + 2];
      a3 += kc * vs[jj][d0 + 3];
    }
    if (tid < 32) {
#pragma unroll
      for (int jj = 0; jj < 16; ++jj) ksum_acc += ks[jj][tid];
    }
  }
  float* kvo = kvp + ((size_t)chunk * 128 + bh) * 1024 + c * 32 + d0;
  kvo[0] = a0; kvo[1] = a1; kvo[2] = a2; kvo[3] = a3;
  if (tid < 32) ksp[((size_t)chunk * 128 + bh) * 32 + tid] = ksum_acc;
}

// ---------------------------------------------------------------------------
// K3b: reduce 8 chunks -> kv_buf [128][1024], ksum_buf [128][32]
// ---------------------------------------------------------------------------
__global__ __launch_bounds__(256) void k_kv_reduce(
    const float* __restrict__ kvp, const float* __restrict__ ksp,
    float* __restrict__ kv, float* __restrict__ ksum) {
  const int bh = blockIdx.x;
  for (int p = threadIdx.x; p < 1024; p += 256) {
    float s = 0.f;
#pragma unroll
    for (int ch = 0; ch < 8; ++ch) s += kvp[((size_t)ch * 128 + bh) * 1024 + p];
    kv[bh * 1024 + p] = s;
  }
  if (threadIdx.x < 32) {
    float s = 0.f;
#pragma unroll
    for (int ch = 0; ch < 8; ++ch)
      s += ksp[((size_t)ch * 128 + bh) * 32 + threadIdx.x];
    ksum[bh * 32 + threadIdx.x] = s;
  }
}

// ---------------------------------------------------------------------------
// K4: fused attn-out + depthwise 5x5 conv; writes bf16 into q-slot of qkv.
// ROUND-5 RESTRUCTURE: thread = (token, 8-channel group) instead of
// (token, all 32 channels). Old version needed ~112 live floats/thread ->
// VGPR=256 + scratch spills -> 2 GB of HBM spill traffic, 634 us.
// Per-thread state now: sacc[8] + fm[8] + transient 8 -> no spills.
// Block = 64 tokens (one image row) x 4 groups; grid = (64 rows, 128 bh).
// ---------------------------------------------------------------------------
__global__ __launch_bounds__(256) void k_attn_conv(
    unsigned short* __restrict__ qkv, const float* __restrict__ kv,
    const float* __restrict__ ksum, const float* __restrict__ dwc_w,
    const float* __restrict__ dwc_b) {
  const int bh = blockIdx.y;
  const int b = bh >> 3, h = bh & 7;
  const int tid = threadIdx.x;
  const int j = tid >> 2;             // token within row = image col (0..63)
  const int g = tid & 3;              // channel group
  const int d0 = g * 8;
  const int i = blockIdx.x;           // image row
  const int n = i * 64 + j;

  __shared__ float kv_s[1024];        // [c][d]
  __shared__ float ksum_s[32];
  __shared__ float w_s[800];          // [tap][ch]
  __shared__ float b_s[32];
  for (int p = tid; p < 1024; p += 256) kv_s[p] = kv[bh * 1024 + p];
  if (tid < 32) ksum_s[tid] = ksum[bh * 32 + tid];
  for (int p = tid; p < 800; p += 256)
    w_s[p] = dwc_w[(p & 31) * 25 + (p >> 5)];
  if (tid < 32) b_s[tid] = dwc_b[tid];
  __syncthreads();

  // ---- attention: out_d = z * sum_c q_c kv[c][d], d in [d0, d0+8)
  const unsigned short* qrow = qkv + ((size_t)(b * N_ + n)) * QKVC + h * HD_;
  float sacc[8] = {0.f, 0.f, 0.f, 0.f, 0.f, 0.f, 0.f, 0.f};
  float zden = 0.f;
#pragma unroll
  for (int cc = 0; cc < 4; ++cc) {
    union { uint4 u; unsigned short s[8]; } qld;
    qld.u = *reinterpret_cast<const uint4*>(qrow + cc * 8);
#pragma unroll
    for (int t = 0; t < 8; ++t) {
      const int c = cc * 8 + t;
      const float qc = b2f(qld.s[t]);
      zden += qc * ksum_s[c];
      const f32x4 kva = *reinterpret_cast<const f32x4*>(&kv_s[c * 32 + d0]);
      const f32x4 kvb = *reinterpret_cast<const f32x4*>(&kv_s[c * 32 + d0 + 4]);
      sacc[0] += qc * kva[0]; sacc[1] += qc * kva[1];
      sacc[2] += qc * kva[2]; sacc[3] += qc * kva[3];
      sacc[4] += qc * kvb[0]; sacc[5] += qc * kvb[1];
      sacc[6] += qc * kvb[2]; sacc[7] += qc * kvb[3];
    }
  }
  const float z = 1.f / (zden + EPS_);

  // ---- depthwise conv on v (channels d0..d0+7)
  float fm[8];
#pragma unroll
  for (int dd = 0; dd < 8; ++dd) fm[dd] = b_s[d0 + dd];
#pragma unroll
  for (int ki = 0; ki < 5; ++ki) {
    const int ii = i + ki - 2;
    if (ii < 0 || ii >= 64) continue;
#pragma unroll
    for (int kj = 0; kj < 5; ++kj) {
      const int jj = j + kj - 2;
      if (jj < 0 || jj >= 64) continue;
      union { uint4 u; unsigned short s[8]; } vld;
      vld.u = *reinterpret_cast<const uint4*>(
          qkv + ((size_t)(b * N_ + ii * 64 + jj)) * QKVC + 2 * C_ + h * HD_ + d0);
      const int t = ki * 5 + kj;
#pragma unroll
      for (int dd = 0; dd < 8; ++dd)
        fm[dd] += b2f(vld.s[dd]) * w_s[t * 32 + d0 + dd];
    }
  }

  // ---- combine + store 16 B (4 threads -> 64 B contiguous per token)
  union { uint4 u; unsigned short s[8]; } st;
#pragma unroll
  for (int dd = 0; dd < 8; ++dd) st.s[dd] = f2b(z * sacc[dd] + fm[dd]);
  *reinterpret_cast<uint4*>(
      qkv + ((size_t)(b * N_ + n)) * QKVC + h * HD_ + d0) = st.u;
}

// ---------------------------------------------------------------------------
extern "C" void kernel_launch(void* const* d_in, const int* in_sizes, int n_in,
                              void* d_out, int out_size, void* d_ws,
                              size_t ws_size, hipStream_t stream) {
  (void)in_sizes; (void)n_in; (void)out_size; (void)ws_size;
  const float* x      = (const float*)d_in[0];
  const float* qkv_w  = (const float*)d_in[1];
  const float* qkv_b  = (const float*)d_in[2];
  const float* proj_w = (const float*)d_in[3];
  const float* proj_b = (const float*)d_in[4];
  const float* dwc_w  = (const float*)d_in[5];
  const float* dwc_b  = (const float*)d_in[6];
  const float* scale  = (const float*)d_in[7];
  float* out = (float*)d_out;

  char* w = (char*)d_ws;
  unsigned short* xT   = (unsigned short*)w; w += (size_t)M_ * C_ * 2;     // 33.6MB
  unsigned short* qkvb = (unsigned short*)w; w += (size_t)M_ * QKVC * 2;   // 100.7MB
  // Reserve space for BOTH weight matrices (round-3 NaN was wp aliasing kvp).
  unsigned short* wq   = (unsigned short*)w; w += (size_t)(QKVC + C_) * C_ * 2;
  unsigned short* wp   = wq + (size_t)QKVC * C_;
  float* kvp   = (float*)w;                  w += (size_t)8 * 128 * 1024 * 4;
  float* ksp   = (float*)w;                  w += (size_t)8 * 128 * 32 * 4;
  float* kvb   = (float*)w;                  w += 128 * 1024 * 4;
  float* ksumb = (float*)w;                  w += 128 * 32 * 4;

  k_cast_x<<<dim3(N_ / 32, C_ / 32, B_), 256, 0, stream>>>(x, xT);
  k_cast_w<<<256, 256, 0, stream>>>(qkv_w, proj_w, wq);
  k_gemm<256, 0><<<dim3(M_ / 128, QKVC / 128), 256, 0, stream>>>(
      xT, wq, qkv_b, (void*)qkvb);
  k_focus<<<M_, 256, 0, stream>>>(qkvb, scale);
  k_kv_part<<<dim3(128, 8), 256, 0, stream>>>(qkvb, kvp, ksp);
  k_kv_reduce<<<128, 256, 0, stream>>>(kvp, ksp, kvb, ksumb);
  k_attn_conv<<<dim3(64, 128), 256, 0, stream>>>(qkvb, kvb, ksumb,
                                                 dwc_w, dwc_b);
  k_gemm<768, 1><<<dim3(M_ / 128, C_ / 128), 256, 0, stream>>>(
      qkvb, wp, proj_b, (void*)out);
}